// Round 13
// baseline (665.799 us; speedup 1.0000x reference)
//
#include <hip/hip_runtime.h>
#include <hip/hip_bf16.h>

#define B_SEG 16384
#define R_EDGE 262144
#define DKDIM 512
#define DOUT 512

#define PBM 128
#define PBN 128
#define PBK 64
#define NBAND 128      // B_SEG / PBM
#define NTILE 512      // NBAND * (DOUT / PBN)
#define NCHUNK 4096    // B_SEG / 4
#define NCONS 64

typedef __attribute__((ext_vector_type(4))) float f32x4;
typedef __attribute__((ext_vector_type(8))) short bf16x8;
typedef __attribute__((ext_vector_type(4))) unsigned short u16x4;

static __device__ __forceinline__ unsigned short f2bf(float f) {
    union { float f; unsigned int u; } v; v.f = f;
    unsigned int r = (v.u + 0x7FFFu + ((v.u >> 16) & 1u)) >> 16;
    return (unsigned short)r;
}

static __device__ __forceinline__ float dot8v(const f32x4 qa, const f32x4 qb,
                                              const f32x4 ka, const f32x4 kb) {
    return qa[0] * ka[0] + qa[1] * ka[1] + qa[2] * ka[2] + qa[3] * ka[3]
         + qb[0] * kb[0] + qb[1] * kb[1] + qb[2] * kb[2] + qb[3] * kb[3];
}

#define GLOAD_LDS(gsrc, ldst)                                                                \
    __builtin_amdgcn_global_load_lds(                                                        \
        (const __attribute__((address_space(1))) void*)(gsrc),                               \
        (__attribute__((address_space(3))) void*)(ldst), 16, 0, 0)

// Fused producer-consumer kernel.
// Blocks 0..63: W_o-transpose tile, signal wtdone, then proj-consume.
// Blocks 64..511: work-steal attn chunks (4 segments), NT ctx stores,
//   release-add bandcnt[band]; after pool drains, join proj.
// Proj: grab tile t (band order), acquire-spin on bandcnt[tile_m]==128,
//   run r10's swizzled-LDS 128x128 GEMM tile.
__global__ __launch_bounds__(512, 4) void fused_kernel(
    const float* __restrict__ Q, const float* __restrict__ K,
    const int* __restrict__ td, unsigned short* __restrict__ ctxb,
    const float* __restrict__ W, unsigned short* __restrict__ Wt,
    const float* __restrict__ bias, float* __restrict__ out,
    int* __restrict__ ctl)
{
    __shared__ unsigned short smem[2 * PBM * PBK + 2 * PBN * PBK];  // 64 KB
    __shared__ int bcast;

    int* segctr  = ctl + 0;
    int* projctr = ctl + 1;
    int* wtdone  = ctl + 2;
    int* bandcnt = ctl + 4;

    const int tid  = (int)threadIdx.x;
    const int lane = tid & 63;

    if (blockIdx.x < NCONS) {
        // ---- consumer prologue: one 64x64 W_o transpose tile ----
        const int c  = (int)blockIdx.x;
        const int n0 = (c & 7) * 64, k0 = (c >> 3) * 64;
        const int col = tid & 63, g = tid >> 6;   // g in 0..7
        #pragma unroll
        for (int j = 0; j < 8; ++j) {
            const int k = g * 8 + j;
            smem[col * 68 + k] = f2bf(W[(size_t)(k0 + k) * DOUT + n0 + col]);
        }
        __syncthreads();
        #pragma unroll
        for (int j = 0; j < 8; ++j) {
            const int r = g * 8 + j;
            Wt[(size_t)(n0 + r) * DKDIM + k0 + col] = smem[r * 68 + col];
        }
        __threadfence();                          // write back dirty Wt lines
        __syncthreads();
        if (tid == 0)
            __hip_atomic_fetch_add(wtdone, 1, __ATOMIC_RELEASE,
                                   __HIP_MEMORY_SCOPE_AGENT);
    } else {
        // ---- producer: work-steal chunks of 4 consecutive segments ----
        while (true) {
            int ck;
            if (lane == 0) ck = atomicAdd(segctr, 1);
            ck = __shfl(ck, 0, 64);
            if (ck >= NCHUNK) break;
            const int b0 = ck << 2;

            // 5 interleaved wave-parallel lower_bounds: lo[j]=lb(td, b0+j)
            int lo[5];
            #pragma unroll
            for (int j = 0; j < 5; ++j) lo[j] = 0;
            #pragma unroll
            for (int S = 4096; S >= 1; S /= 64) {   // 4096, 64, 1
                #pragma unroll
                for (int j = 0; j < 5; ++j) {
                    const int v = td[lo[j] + lane * S];
                    const int cnt = __popcll(__ballot(v < b0 + j));
                    lo[j] += (S > 1) ? ((cnt ? cnt - 1 : 0) * S) : cnt;
                }
            }

            #pragma unroll
            for (int j = 0; j < 4; ++j) {
                const int s0 = lo[j], s1 = lo[j + 1];
                const int b = b0 + j;
                const f32x4* Q4 = (const f32x4*)(Q + (size_t)b * DKDIM);
                const f32x4 qa = __builtin_nontemporal_load(Q4 + lane);
                const f32x4 qb = __builtin_nontemporal_load(Q4 + 64 + lane);
                float m = -INFINITY, l = 0.0f;
                float c0 = 0, c1 = 0, c2 = 0, c3 = 0, c4 = 0, c5 = 0, c6 = 0, c7 = 0;
                for (int e = s0; e < s1; ++e) {
                    const f32x4* K4 = (const f32x4*)(K + (size_t)e * DKDIM);
                    const f32x4 ka = __builtin_nontemporal_load(K4 + lane);
                    const f32x4 kb = __builtin_nontemporal_load(K4 + 64 + lane);
                    float p = dot8v(qa, qb, ka, kb);
                    #pragma unroll
                    for (int off = 32; off >= 1; off >>= 1) p += __shfl_xor(p, off, 64);
                    if (p > m + 8.0f) {            // defer-max, wave-uniform
                        const float sc = __expf(m - p);
                        l *= sc;
                        c0 *= sc; c1 *= sc; c2 *= sc; c3 *= sc;
                        c4 *= sc; c5 *= sc; c6 *= sc; c7 *= sc;
                        m = p;
                    }
                    const float wgt = __expf(p - m);
                    l += wgt;
                    c0 += wgt * ka[0]; c1 += wgt * ka[1];
                    c2 += wgt * ka[2]; c3 += wgt * ka[3];
                    c4 += wgt * kb[0]; c5 += wgt * kb[1];
                    c6 += wgt * kb[2]; c7 += wgt * kb[3];
                }
                const float rin = (s1 > s0) ? (1.0f / l) : 0.0f;
                u16x4 oa, ob;
                oa[0] = f2bf(c0 * rin); oa[1] = f2bf(c1 * rin);
                oa[2] = f2bf(c2 * rin); oa[3] = f2bf(c3 * rin);
                ob[0] = f2bf(c4 * rin); ob[1] = f2bf(c5 * rin);
                ob[2] = f2bf(c6 * rin); ob[3] = f2bf(c7 * rin);
                u16x4* O4 = (u16x4*)(ctxb + (size_t)b * DKDIM);
                __builtin_nontemporal_store(oa, O4 + lane);       // NT: no L2 dirty
                __builtin_nontemporal_store(ob, O4 + 64 + lane);  // lines to flush
            }
            __threadfence();                       // ctx stores reach L3 coherence pt
            if (lane == 0)
                __hip_atomic_fetch_add(&bandcnt[b0 >> 7], 4, __ATOMIC_RELEASE,
                                       __HIP_MEMORY_SCOPE_AGENT);
        }
    }

    // ---- join: everyone becomes a proj consumer ----
    __syncthreads();
    if (tid == 0) {
        while (__hip_atomic_load(wtdone, __ATOMIC_ACQUIRE,
                                 __HIP_MEMORY_SCOPE_AGENT) < NCONS)
            __builtin_amdgcn_s_sleep(2);
    }
    __syncthreads();

    const int w  = tid >> 6;
    const int lr = lane & 15, lg = lane >> 4;
    const int wr = w >> 2, wc = w & 3;             // wave quadrant: 2m x 4n
    const int srow = lane >> 3;                    // staging row-within-8
    const int scol = ((lane & 7) ^ srow) * 8;      // pre-swizzled global k-offset

    unsigned short* ldsA0 = smem;                  // [2][PBM*PBK]
    unsigned short* ldsB0 = smem + 2 * PBM * PBK;  // [2][PBN*PBK]

#define STAGE(buf, ks)                                                                       \
    {                                                                                        \
        const int k0_ = (ks) * PBK;                                                          \
        GLOAD_LDS(ctxb + (size_t)(mrow + w * 16 + srow) * DKDIM + k0_ + scol,                \
                  ldsA0 + (buf) * PBM * PBK + (w * 16) * PBK);                               \
        GLOAD_LDS(ctxb + (size_t)(mrow + w * 16 + 8 + srow) * DKDIM + k0_ + scol,            \
                  ldsA0 + (buf) * PBM * PBK + (w * 16 + 8) * PBK);                           \
        GLOAD_LDS(Wt + (size_t)(ncol0 + w * 16 + srow) * DKDIM + k0_ + scol,                 \
                  ldsB0 + (buf) * PBN * PBK + (w * 16) * PBK);                               \
        GLOAD_LDS(Wt + (size_t)(ncol0 + w * 16 + 8 + srow) * DKDIM + k0_ + scol,             \
                  ldsB0 + (buf) * PBN * PBK + (w * 16 + 8) * PBK);                           \
    }

    while (true) {
        if (tid == 0) bcast = atomicAdd(projctr, 1);
        __syncthreads();
        const int t = bcast;
        if (t >= NTILE) break;
        const int tile_m = t >> 2, tile_n = t & 3;   // band order == ready order
        if (tid == 0) {
            while (__hip_atomic_load(&bandcnt[tile_m], __ATOMIC_ACQUIRE,
                                     __HIP_MEMORY_SCOPE_AGENT) < PBM)
                __builtin_amdgcn_s_sleep(2);
            __threadfence();
        }
        __syncthreads();                             // also fences bcast reuse

        const int mrow  = tile_m * PBM;
        const int ncol0 = tile_n * PBN;

        f32x4 acc[4][2];
        #pragma unroll
        for (int i = 0; i < 4; ++i)
            #pragma unroll
            for (int jj = 0; jj < 2; ++jj)
                acc[i][jj] = (f32x4){0.f, 0.f, 0.f, 0.f};

        STAGE(0, 0);
        __syncthreads();                             // drains vmcnt -> buf0 ready

        int cur = 0;
        for (int ks = 0; ks < DKDIM / PBK; ++ks) {   // 8 K-steps
            if (ks + 1 < DKDIM / PBK) STAGE(cur ^ 1, ks + 1);
            bf16x8 af[4][2], bfr[2][2];
            #pragma unroll
            for (int kk = 0; kk < 2; ++kk) {
                #pragma unroll
                for (int mq = 0; mq < 4; ++mq) {
                    const int ra = wr * 64 + mq * 16 + lr;
                    af[mq][kk] = *(const bf16x8*)
                        &ldsA0[cur * PBM * PBK + ra * PBK + (((kk << 2) | lg) ^ (ra & 7)) * 8];
                }
                #pragma unroll
                for (int nq = 0; nq < 2; ++nq) {
                    const int rb = wc * 32 + nq * 16 + lr;
                    bfr[nq][kk] = *(const bf16x8*)
                        &ldsB0[cur * PBN * PBK + rb * PBK + (((kk << 2) | lg) ^ (rb & 7)) * 8];
                }
            }
            #pragma unroll
            for (int kk = 0; kk < 2; ++kk)
                #pragma unroll
                for (int mq = 0; mq < 4; ++mq)
                    #pragma unroll
                    for (int nq = 0; nq < 2; ++nq)
                        acc[mq][nq] = __builtin_amdgcn_mfma_f32_16x16x32_bf16(
                            af[mq][kk], bfr[nq][kk], acc[mq][nq], 0, 0, 0);
            __syncthreads();
            cur ^= 1;
        }

        #pragma unroll
        for (int mq = 0; mq < 4; ++mq) {
            #pragma unroll
            for (int nq = 0; nq < 2; ++nq) {
                const int col = ncol0 + wc * 32 + nq * 16 + lr;
                const float bb = bias[col];
                #pragma unroll
                for (int r = 0; r < 4; ++r) {
                    const int row = mrow + wr * 64 + mq * 16 + lg * 4 + r;  // m89 C/D
                    __builtin_nontemporal_store(acc[mq][nq][r] + bb,
                                                &out[(size_t)row * DOUT + col]);
                }
            }
        }
    }
}

extern "C" void kernel_launch(void* const* d_in, const int* in_sizes, int n_in,
                              void* d_out, int out_size, void* d_ws, size_t ws_size,
                              hipStream_t stream) {
    const float* Q  = (const float*)d_in[0];
    const float* K  = (const float*)d_in[1];
    const int*   td = (const int*)d_in[2];
    const float* Wo = (const float*)d_in[3];
    const float* bo = (const float*)d_in[4];
    float* out = (float*)d_out;

    unsigned short* ctxb = (unsigned short*)d_ws;                  // 16.8 MB
    unsigned short* Wt   = ctxb + (size_t)B_SEG * DKDIM;           // + 0.5 MB
    int* ctl = (int*)(Wt + (size_t)DOUT * DKDIM);                  // + 528 B

    // counters must be zero every call (graph replays don't re-poison ws)
    (void)hipMemsetAsync(ctl, 0, (4 + NBAND) * sizeof(int), stream);
    hipLaunchKernelGGL(fused_kernel, dim3(512), dim3(512), 0, stream,
                       Q, K, td, ctxb, Wo, Wt, bo, out, ctl);
}

// Round 14
// 123.979 us; speedup vs baseline: 5.3703x; 5.3703x over previous
//
#include <hip/hip_runtime.h>
#include <hip/hip_bf16.h>

#define B_SEG 16384
#define R_EDGE 262144
#define DKDIM 512
#define DOUT 512

typedef __attribute__((ext_vector_type(4))) float f32x4;
typedef __attribute__((ext_vector_type(8))) short bf16x8;

static __device__ __forceinline__ unsigned short f2bf(float f) {
    union { float f; unsigned int u; } v; v.f = f;
    unsigned int r = (v.u + 0x7FFFu + ((v.u >> 16) & 1u)) >> 16;
    return (unsigned short)r;
}

static __device__ __forceinline__ float dot8v(const f32x4 qa, const f32x4 qb,
                                              const f32x4 ka, const f32x4 kb) {
    return qa[0] * ka[0] + qa[1] * ka[1] + qa[2] * ka[2] + qa[3] * ka[3]
         + qb[0] * kb[0] + qb[1] * kb[1] + qb[2] * kb[2] + qb[3] * kb[3];
}

// ---------------- Stage 1: fused segment attention (+hidden W_o transpose) ---
// Blocks 0..63 (dispatched first, hidden under attn): 64x64 LDS tile transpose
// of W_o into bf16 Wt. Blocks 64..16447: one segment per 64-thread block.
// Segment bounds via IN-KERNEL wave-parallel lower_bound (3 ballot rounds,
// 262144->4096->64->exact; all blocks share probe positions -> L1/L2-hot) —
// no separate starts kernel. Online softmax with defer-max. K/Q loads
// NON-TEMPORAL (read-once streams).
__global__ __launch_bounds__(64, 6) void attn_kernel(
    const float* __restrict__ Q, const float* __restrict__ K,
    const int* __restrict__ td, unsigned short* __restrict__ ctxb,
    const float* __restrict__ W, unsigned short* __restrict__ Wt)
{
    __shared__ unsigned short tile[64][68];
    const int lane = threadIdx.x & 63;

    if (blockIdx.x < 64) {                    // W_o transpose, runs first, hidden
        const int bb = blockIdx.x;
        const int n0 = (bb & 7) * 64;
        const int k0 = (bb >> 3) * 64;
        for (int k = 0; k < 64; ++k)
            tile[lane][k] = f2bf(W[(size_t)(k0 + k) * DOUT + n0 + lane]);  // coalesced
        __syncthreads();
        for (int r = 0; r < 64; ++r)
            Wt[(size_t)(n0 + r) * DKDIM + k0 + lane] = tile[r][lane];      // coalesced
        return;
    }

    const int b = blockIdx.x - 64;

    // Dual wave-parallel lower_bound(td, b) / lower_bound(td, b+1).
    // Invariant: lb in [lo, lo+range]; probes lo+i*S keep prefix property.
    int loA = 0, loB = 0;
    #pragma unroll
    for (int S = 4096; S >= 1; S /= 64) {     // 4096, 64, 1
        const int va = td[loA + lane * S];
        const int vb = td[loB + lane * S];
        const int cA = __popcll(__ballot(va < b));
        const int cB = __popcll(__ballot(vb < b + 1));
        if (S > 1) {
            loA += (cA ? cA - 1 : 0) * S;
            loB += (cB ? cB - 1 : 0) * S;
        } else {
            loA += cA;
            loB += cB;
        }
    }
    const int s0 = loA;
    const int s1 = loB;

    const f32x4* Q4 = (const f32x4*)(Q + (size_t)b * DKDIM);
    const f32x4 qa = __builtin_nontemporal_load(Q4 + lane);
    const f32x4 qb = __builtin_nontemporal_load(Q4 + 64 + lane);

    float m = -INFINITY, l = 0.0f;
    float c0 = 0.f, c1 = 0.f, c2 = 0.f, c3 = 0.f;
    float c4 = 0.f, c5 = 0.f, c6 = 0.f, c7 = 0.f;

    f32x4 ka0, kb0, ka1, kb1, ka2, kb2, ka3, kb3;

#define LOAD4(dst_a0, dst_b0, dst_a1, dst_b1, dst_a2, dst_b2, dst_a3, dst_b3, ee)            \
    {                                                                                        \
        const f32x4* K0_ = (const f32x4*)(K + (size_t)((ee) + 0) * DKDIM);                   \
        const f32x4* K1_ = (const f32x4*)(K + (size_t)((ee) + 1) * DKDIM);                   \
        const f32x4* K2_ = (const f32x4*)(K + (size_t)((ee) + 2) * DKDIM);                   \
        const f32x4* K3_ = (const f32x4*)(K + (size_t)((ee) + 3) * DKDIM);                   \
        dst_a0 = __builtin_nontemporal_load(K0_ + lane);                                     \
        dst_b0 = __builtin_nontemporal_load(K0_ + 64 + lane);                                \
        dst_a1 = __builtin_nontemporal_load(K1_ + lane);                                     \
        dst_b1 = __builtin_nontemporal_load(K1_ + 64 + lane);                                \
        dst_a2 = __builtin_nontemporal_load(K2_ + lane);                                     \
        dst_b2 = __builtin_nontemporal_load(K2_ + 64 + lane);                                \
        dst_a3 = __builtin_nontemporal_load(K3_ + lane);                                     \
        dst_b3 = __builtin_nontemporal_load(K3_ + 64 + lane);                                \
    }

#define PROC4()                                                                              \
    {                                                                                        \
        float p0 = dot8v(qa, qb, ka0, kb0);                                                  \
        float p1 = dot8v(qa, qb, ka1, kb1);                                                  \
        float p2 = dot8v(qa, qb, ka2, kb2);                                                  \
        float p3 = dot8v(qa, qb, ka3, kb3);                                                  \
        _Pragma("unroll")                                                                    \
        for (int off = 32; off >= 1; off >>= 1) {                                            \
            p0 += __shfl_xor(p0, off, 64);                                                   \
            p1 += __shfl_xor(p1, off, 64);                                                   \
            p2 += __shfl_xor(p2, off, 64);                                                   \
            p3 += __shfl_xor(p3, off, 64);                                                   \
        }                                                                                    \
        const float gmax = fmaxf(fmaxf(p0, p1), fmaxf(p2, p3));                              \
        if (gmax > m + 8.0f) {   /* wave-uniform branch; m=-inf first group */               \
            const float sc = __expf(m - gmax);                                               \
            l *= sc;                                                                         \
            c0 *= sc; c1 *= sc; c2 *= sc; c3 *= sc;                                          \
            c4 *= sc; c5 *= sc; c6 *= sc; c7 *= sc;                                          \
            m = gmax;                                                                        \
        }                                                                                    \
        const float w0 = __expf(p0 - m), w1 = __expf(p1 - m);                                \
        const float w2 = __expf(p2 - m), w3 = __expf(p3 - m);                                \
        l += (w0 + w1) + (w2 + w3);                                                          \
        c0 += (w0 * ka0[0] + w1 * ka1[0]) + (w2 * ka2[0] + w3 * ka3[0]);                     \
        c1 += (w0 * ka0[1] + w1 * ka1[1]) + (w2 * ka2[1] + w3 * ka3[1]);                     \
        c2 += (w0 * ka0[2] + w1 * ka1[2]) + (w2 * ka2[2] + w3 * ka3[2]);                     \
        c3 += (w0 * ka0[3] + w1 * ka1[3]) + (w2 * ka2[3] + w3 * ka3[3]);                     \
        c4 += (w0 * kb0[0] + w1 * kb1[0]) + (w2 * kb2[0] + w3 * kb3[0]);                     \
        c5 += (w0 * kb0[1] + w1 * kb1[1]) + (w2 * kb2[1] + w3 * kb3[1]);                     \
        c6 += (w0 * kb0[2] + w1 * kb1[2]) + (w2 * kb2[2] + w3 * kb3[2]);                     \
        c7 += (w0 * kb0[3] + w1 * kb1[3]) + (w2 * kb2[3] + w3 * kb3[3]);                     \
    }

    int e = s0;
    if (s1 - s0 >= 4) {
        LOAD4(ka0, kb0, ka1, kb1, ka2, kb2, ka3, kb3, e);
        for (; e + 7 < s1; e += 4) {
            f32x4 na0, nb0, na1, nb1, na2, nb2, na3, nb3;
            LOAD4(na0, nb0, na1, nb1, na2, nb2, na3, nb3, e + 4);   // prefetch next
            PROC4();                                                 // compute current
            ka0 = na0; kb0 = nb0; ka1 = na1; kb1 = nb1;
            ka2 = na2; kb2 = nb2; ka3 = na3; kb3 = nb3;
        }
        PROC4();
        e += 4;
    }
    for (; e < s1; ++e) {
        const f32x4* K4 = (const f32x4*)(K + (size_t)e * DKDIM);
        const f32x4 ka = __builtin_nontemporal_load(K4 + lane);
        const f32x4 kb = __builtin_nontemporal_load(K4 + 64 + lane);
        float p = dot8v(qa, qb, ka, kb);
        #pragma unroll
        for (int off = 32; off >= 1; off >>= 1) p += __shfl_xor(p, off, 64);
        if (p > m + 8.0f) {
            const float sc = __expf(m - p);
            l *= sc;
            c0 *= sc; c1 *= sc; c2 *= sc; c3 *= sc;
            c4 *= sc; c5 *= sc; c6 *= sc; c7 *= sc;
            m = p;
        }
        const float wgt = __expf(p - m);
        l += wgt;
        c0 += wgt * ka[0];  c1 += wgt * ka[1];
        c2 += wgt * ka[2];  c3 += wgt * ka[3];
        c4 += wgt * kb[0];  c5 += wgt * kb[1];
        c6 += wgt * kb[2];  c7 += wgt * kb[3];
    }

    const float rin = (s1 > s0) ? (1.0f / l) : 0.0f;  // empty segment -> ctx = 0
    ushort4 oa, ob;
    oa.x = f2bf(c0 * rin); oa.y = f2bf(c1 * rin); oa.z = f2bf(c2 * rin); oa.w = f2bf(c3 * rin);
    ob.x = f2bf(c4 * rin); ob.y = f2bf(c5 * rin); ob.z = f2bf(c6 * rin); ob.w = f2bf(c7 * rin);
    ushort4* O4 = (ushort4*)(ctxb + (size_t)b * DKDIM);
    O4[lane]      = oa;    // normal store: proj re-reads ctx soon (keep in L2)
    O4[64 + lane] = ob;
}

// ---------------- Stage 2: out = ctx @ W_o + b_o (128x128, BK=64, swizzled) --
// 8 waves / 512 threads, each wave a 64x32 quadrant. LDS rows are 128B (8 x
// 16B slots); XOR-swizzle slot ^= (row&7) applied BOTH sides (rule #21):
// staging pre-swizzles the per-lane GLOBAL source (LDS dest linear, as
// global_load_lds requires) and ds_reads apply the same involution -> rows
// r, r+8 alias each slot = 2 lanes/bank (free). A re-read 4x. XCD-bijective
// m-bands. out stores NON-TEMPORAL.
#define PBM 128
#define PBN 128
#define PBK 64

#define GLOAD_LDS(gsrc, ldst)                                                                \
    __builtin_amdgcn_global_load_lds(                                                        \
        (const __attribute__((address_space(1))) void*)(gsrc),                               \
        (__attribute__((address_space(3))) void*)(ldst), 16, 0, 0)

__global__ __launch_bounds__(512, 4) void proj_kernel(
    const unsigned short* __restrict__ A,   // ctx bf16, [16384][512] row-major
    const unsigned short* __restrict__ Bt,  // W_o^T bf16, [512 n][512 k]
    const float* __restrict__ bias, float* __restrict__ out)
{
    __shared__ unsigned short ldsA[2][PBM * PBK];   // 16 KB per buf
    __shared__ unsigned short ldsB[2][PBN * PBK];   // 16 KB per buf

    const int w = threadIdx.x >> 6, lane = threadIdx.x & 63;
    // XCD-bijective: 512 blocks = 8 XCDs x 64; each XCD a 16-tile m-band.
    const int x = (int)blockIdx.x & 7, idx = (int)blockIdx.x >> 3;  // idx 0..63
    const int tile_m = x * 16 + (idx >> 2);   // 0..127
    const int tile_n = idx & 3;               // 0..3
    const int mrow  = tile_m * PBM;
    const int ncol0 = tile_n * PBN;
    const int wr = w >> 2, wc = w & 3;        // wave quadrant: 2m x 4n
    const int lr = lane & 15, lg = lane >> 4;

    // staging: 8 lanes per 128B row; source slot pre-swizzled by row&7
    const int srow = lane >> 3;                         // row-within-8 (== r&7)
    const int scol = ((lane & 7) ^ srow) * 8;           // swizzled k-offset (elems)

#define STAGE(buf, ks)                                                                       \
    {                                                                                        \
        const int k0_ = (ks) * PBK;                                                          \
        GLOAD_LDS(A + (size_t)(mrow + w * 16 + srow) * DKDIM + k0_ + scol,                   \
                  &ldsA[buf][(w * 16) * PBK]);                                               \
        GLOAD_LDS(A + (size_t)(mrow + w * 16 + 8 + srow) * DKDIM + k0_ + scol,               \
                  &ldsA[buf][(w * 16 + 8) * PBK]);                                           \
        GLOAD_LDS(Bt + (size_t)(ncol0 + w * 16 + srow) * DKDIM + k0_ + scol,                 \
                  &ldsB[buf][(w * 16) * PBK]);                                               \
        GLOAD_LDS(Bt + (size_t)(ncol0 + w * 16 + 8 + srow) * DKDIM + k0_ + scol,             \
                  &ldsB[buf][(w * 16 + 8) * PBK]);                                           \
    }

    f32x4 acc[4][2];
    #pragma unroll
    for (int i = 0; i < 4; ++i)
        #pragma unroll
        for (int j = 0; j < 2; ++j)
            acc[i][j] = (f32x4){0.f, 0.f, 0.f, 0.f};

    STAGE(0, 0);
    __syncthreads();   // drains vmcnt -> buf0 ready

    int cur = 0;
    for (int ks = 0; ks < DKDIM / PBK; ++ks) {          // 8 K-steps
        if (ks + 1 < DKDIM / PBK) STAGE(cur ^ 1, ks + 1);   // DMA next while computing
        bf16x8 af[4][2], bfr[2][2];
        #pragma unroll
        for (int kk = 0; kk < 2; ++kk) {
            #pragma unroll
            for (int mq = 0; mq < 4; ++mq) {
                const int ra = wr * 64 + mq * 16 + lr;
                af[mq][kk] = *(const bf16x8*)
                    &ldsA[cur][ra * PBK + (((kk << 2) | lg) ^ (ra & 7)) * 8];
            }
            #pragma unroll
            for (int nq = 0; nq < 2; ++nq) {
                const int rb = wc * 32 + nq * 16 + lr;
                bfr[nq][kk] = *(const bf16x8*)
                    &ldsB[cur][rb * PBK + (((kk << 2) | lg) ^ (rb & 7)) * 8];
            }
        }
        #pragma unroll
        for (int kk = 0; kk < 2; ++kk)
            #pragma unroll
            for (int mq = 0; mq < 4; ++mq)
                #pragma unroll
                for (int nq = 0; nq < 2; ++nq)
                    acc[mq][nq] = __builtin_amdgcn_mfma_f32_16x16x32_bf16(
                        af[mq][kk], bfr[nq][kk], acc[mq][nq], 0, 0, 0);
        __syncthreads();   // next buf ready, reads done
        cur ^= 1;
    }

    #pragma unroll
    for (int mq = 0; mq < 4; ++mq) {
        #pragma unroll
        for (int nq = 0; nq < 2; ++nq) {
            const int col = ncol0 + wc * 32 + nq * 16 + lr;
            const float bb = bias[col];
            #pragma unroll
            for (int r = 0; r < 4; ++r) {
                const int row = mrow + wr * 64 + mq * 16 + lg * 4 + r;  // m89 C/D layout
                __builtin_nontemporal_store(acc[mq][nq][r] + bb,
                                            &out[(size_t)row * DOUT + col]);
            }
        }
    }
}

extern "C" void kernel_launch(void* const* d_in, const int* in_sizes, int n_in,
                              void* d_out, int out_size, void* d_ws, size_t ws_size,
                              hipStream_t stream) {
    const float* Q  = (const float*)d_in[0];
    const float* K  = (const float*)d_in[1];
    const int*   td = (const int*)d_in[2];
    const float* Wo = (const float*)d_in[3];
    const float* bo = (const float*)d_in[4];
    float* out = (float*)d_out;

    unsigned short* ctxb = (unsigned short*)d_ws;                  // 16.8 MB
    unsigned short* Wt   = ctxb + (size_t)B_SEG * DKDIM;           // + 0.5 MB

    hipLaunchKernelGGL(attn_kernel, dim3(B_SEG + 64), dim3(64), 0, stream,
                       Q, K, td, ctxb, Wo, Wt);
    hipLaunchKernelGGL(proj_kernel, dim3((B_SEG / PBM) * (DOUT / PBN)), dim3(512), 0, stream,
                       ctxb, Wt, bo, out);
}